// Round 1
// baseline (984.376 us; speedup 1.0000x reference)
//
#include <hip/hip_runtime.h>

// LMFreezeConcatModel: lm = X@W_lm+b ; 3x GCNConv(norm-sym, self-loops) ; concat -> W_cls.
// Pipeline: CSR build (hist+scan+fill) -> bf16 MFMA GEMMs -> gather aggregation -> classifier.

using bf16x8 = __attribute__((ext_vector_type(8))) short;
using f32x4  = __attribute__((ext_vector_type(4))) float;
typedef unsigned short u16;
typedef unsigned int   u32;

__device__ __forceinline__ u16 f2bf(float f) {
  u32 u = __builtin_bit_cast(u32, f);
  u += 0x7fffu + ((u >> 16) & 1u);          // round-to-nearest-even
  return (u16)(u >> 16);
}
__device__ __forceinline__ float bf2f(u32 lo16) {
  return __builtin_bit_cast(float, lo16 << 16);
}
__device__ __forceinline__ u32 packbf2(float a, float b) {
  return (u32)f2bf(a) | ((u32)f2bf(b) << 16);
}

// ---------------- degree / CSR build ----------------

__global__ void count_kernel(const int* __restrict__ dst, int* __restrict__ counts, int E) {
  int e = blockIdx.x * 256 + threadIdx.x;
  if (e < E) atomicAdd(&counts[dst[e]], 1);
}

__global__ void dinv_kernel(const int* __restrict__ counts, float* __restrict__ dinv, int N) {
  int i = blockIdx.x * 256 + threadIdx.x;
  if (i < N) dinv[i] = rsqrtf((float)(counts[i] + 1));   // +1 self-loop; deg>=1 always
}

// two-level exclusive scan over counts[N] -> offsets[N]
__global__ void scan_partial(const int* __restrict__ counts, int* __restrict__ partials, int N) {
  __shared__ int sdata[256];
  int t = threadIdx.x;
  int base = blockIdx.x * 1024 + t * 4;
  int s = 0;
#pragma unroll
  for (int i = 0; i < 4; i++) { int idx = base + i; if (idx < N) s += counts[idx]; }
  sdata[t] = s; __syncthreads();
  for (int off = 128; off > 0; off >>= 1) {
    if (t < off) sdata[t] += sdata[t + off];
    __syncthreads();
  }
  if (t == 0) partials[blockIdx.x] = sdata[0];
}

__global__ void scan_partials_excl(int* __restrict__ partials, int NB,
                                   int* __restrict__ offsets, int N, int E) {
  __shared__ int sdata[256];
  int t = threadIdx.x;
  int v = (t < NB) ? partials[t] : 0;
  sdata[t] = v; __syncthreads();
  int val = v;
  for (int off = 1; off < 256; off <<= 1) {
    int add = (t >= off) ? sdata[t - off] : 0;
    __syncthreads();
    val += add; sdata[t] = val;
    __syncthreads();
  }
  if (t < NB) partials[t] = val - v;   // exclusive
  if (t == 0) offsets[N] = E;
}

__global__ void scan_final(const int* __restrict__ counts, const int* __restrict__ partials,
                           int* __restrict__ offsets, int N) {
  __shared__ int sdata[256];
  int t = threadIdx.x;
  int base = blockIdx.x * 1024 + t * 4;
  int v[4]; int tsum = 0;
#pragma unroll
  for (int i = 0; i < 4; i++) { int idx = base + i; v[i] = (idx < N) ? counts[idx] : 0; tsum += v[i]; }
  sdata[t] = tsum; __syncthreads();
  int val = tsum;
  for (int off = 1; off < 256; off <<= 1) {
    int add = (t >= off) ? sdata[t - off] : 0;
    __syncthreads();
    val += add; sdata[t] = val;
    __syncthreads();
  }
  int run = partials[blockIdx.x] + val - tsum;
#pragma unroll
  for (int i = 0; i < 4; i++) { int idx = base + i; if (idx < N) offsets[idx] = run; run += v[i]; }
}

__global__ void fill_kernel(const int* __restrict__ src, const int* __restrict__ dst,
                            const int* __restrict__ offsets, int* __restrict__ cursor,
                            const float* __restrict__ dinv,
                            int* __restrict__ col, float* __restrict__ wn, int E) {
  int e = blockIdx.x * 256 + threadIdx.x;
  if (e < E) {
    int d = dst[e], s = src[e];
    int p = offsets[d] + atomicAdd(&cursor[d], 1);
    col[p] = s;
    wn[p] = dinv[s] * dinv[d];
  }
}

// ---------------- weight prep (transpose + bf16) ----------------

__global__ void prep_wlm(const float* __restrict__ W, u16* __restrict__ Wt) {
  int idx = blockIdx.x * 256 + threadIdx.x;       // over 1024*128
  if (idx < 1024 * 128) {
    int k = idx >> 7, c = idx & 127;
    Wt[c * 1024 + k] = f2bf(W[idx]);              // Wt[col][k]
  }
}
__global__ void prep_wgcn(const float* __restrict__ W, u16* __restrict__ Wt, int total) {
  int idx = blockIdx.x * 256 + threadIdx.x;       // over L*128*128
  if (idx < total) {
    int l = idx >> 14; int r = idx & 16383;
    int k = r >> 7, c = r & 127;
    Wt[l * 16384 + c * 128 + k] = f2bf(W[idx]);
  }
}

// ---------------- bf16 MFMA GEMM: Out[N][128] = A[N][K] @ B[K][128] (+bias) ----------------
// Bt is B transposed: [128][K] bf16. BM=128, BN=128, BK=32, 4 waves, wave = 64x64.

template<int K, bool A_IS_F32, bool ADD_BIAS>
__global__ __launch_bounds__(256) void gemm_kernel(
    const void* __restrict__ Aptr, const u16* __restrict__ Bt,
    const float* __restrict__ bias, u16* __restrict__ Out, int Nrows)
{
  __shared__ u16 lA[128 * 32];
  __shared__ u16 lB[128 * 32];
  const int t = threadIdx.x;
  const int lane = t & 63;
  const int w = t >> 6;
  const int wr = w >> 1, wc = w & 1;
  const int row0 = blockIdx.x * 128;
  const int quad = lane >> 4;
  const int l16 = lane & 15;

  f32x4 acc[4][4];
#pragma unroll
  for (int i = 0; i < 4; i++)
#pragma unroll
    for (int j = 0; j < 4; j++) acc[i][j] = f32x4{0.f, 0.f, 0.f, 0.f};

  for (int k0 = 0; k0 < K; k0 += 32) {
    // --- stage A tile [128][32] ---
    if (A_IS_F32) {
      const float* A = (const float*)Aptr;
#pragma unroll
      for (int rpt = 0; rpt < 2; rpt++) {
        int seg = t + rpt * 256;                  // 0..511
        int row = seg >> 2, ks = seg & 3;
        int grow = row0 + row; if (grow >= Nrows) grow = Nrows - 1;
        const float* gp = A + (size_t)grow * K + k0 + ks * 8;
        float4 f0 = *reinterpret_cast<const float4*>(gp);
        float4 f1 = *reinterpret_cast<const float4*>(gp + 4);
        uint4 pk;
        pk.x = packbf2(f0.x, f0.y); pk.y = packbf2(f0.z, f0.w);
        pk.z = packbf2(f1.x, f1.y); pk.w = packbf2(f1.z, f1.w);
        *reinterpret_cast<uint4*>(&lA[seg * 8]) = pk;
      }
    } else {
      const u16* A = (const u16*)Aptr;
#pragma unroll
      for (int rpt = 0; rpt < 2; rpt++) {
        int seg = t + rpt * 256;
        int row = seg >> 2, ks = seg & 3;
        int grow = row0 + row; if (grow >= Nrows) grow = Nrows - 1;
        const u16* gp = A + (size_t)grow * K + k0 + ks * 8;
        *reinterpret_cast<uint4*>(&lA[seg * 8]) = *reinterpret_cast<const uint4*>(gp);
      }
    }
    // --- stage B tile: lB[col][32] from Bt[128][K] ---
#pragma unroll
    for (int rpt = 0; rpt < 2; rpt++) {
      int seg = t + rpt * 256;
      int c = seg >> 2, ks = seg & 3;
      const u16* gp = Bt + (size_t)c * K + k0 + ks * 8;
      *reinterpret_cast<uint4*>(&lB[seg * 8]) = *reinterpret_cast<const uint4*>(gp);
    }
    __syncthreads();

    bf16x8 af[4], bfr[4];
#pragma unroll
    for (int i = 0; i < 4; i++) {
      int r = wr * 64 + i * 16 + l16;
      af[i] = *reinterpret_cast<const bf16x8*>(&lA[r * 32 + quad * 8]);
    }
#pragma unroll
    for (int j = 0; j < 4; j++) {
      int c = wc * 64 + j * 16 + l16;
      bfr[j] = *reinterpret_cast<const bf16x8*>(&lB[c * 32 + quad * 8]);
    }
    __syncthreads();   // frags in regs; staging of next iter may proceed after MFMAs issue

#pragma unroll
    for (int i = 0; i < 4; i++)
#pragma unroll
      for (int j = 0; j < 4; j++)
        acc[i][j] = __builtin_amdgcn_mfma_f32_16x16x32_bf16(af[i], bfr[j], acc[i][j], 0, 0, 0);
  }

  // epilogue: C/D layout col=lane&15, row=quad*4+reg
#pragma unroll
  for (int i = 0; i < 4; i++) {
    int rbase = row0 + wr * 64 + i * 16 + quad * 4;
#pragma unroll
    for (int j = 0; j < 4; j++) {
      int c = wc * 64 + j * 16 + l16;
      float bv = ADD_BIAS ? bias[c] : 0.f;
#pragma unroll
      for (int r = 0; r < 4; r++) {
        int grow = rbase + r;
        if (grow < Nrows) {
          float v = acc[i][j][r] + bv;
          Out[(size_t)grow * 128 + c] = f2bf(v);
        }
      }
    }
  }
}

// ---------------- aggregation: out[i] = relu( sum_{e:dst=i} wn[e]*h[src] + dinv[i]^2*h[i] + b ) ----
// one wave per dst row; lane covers feature cols 2*lane, 2*lane+1 (bf16 pair per u32)

__global__ __launch_bounds__(256) void aggregate_kernel(
    const u16* __restrict__ h, const int* __restrict__ offsets,
    const int* __restrict__ col, const float* __restrict__ wn,
    const float* __restrict__ dinv, const float* __restrict__ bias,
    u16* __restrict__ outf, int N)
{
  int w = threadIdx.x >> 6;
  int lane = threadIdx.x & 63;
  int i = blockIdx.x * 4 + w;
  if (i >= N) return;
  const u32* h32 = (const u32*)h;
  float di = dinv[i];
  float sw = di * di;
  u32 us = h32[(size_t)i * 64 + lane];
  float ax = sw * bf2f(us & 0xffffu);
  float ay = sw * bf2f(us >> 16);
  int s = offsets[i], e = offsets[i + 1];
  int p = s;
  for (; p + 4 <= e; p += 4) {          // batch-4 for memory-level parallelism
    int j0 = col[p], j1 = col[p + 1], j2 = col[p + 2], j3 = col[p + 3];
    float w0 = wn[p], w1 = wn[p + 1], w2 = wn[p + 2], w3 = wn[p + 3];
    u32 u0 = h32[(size_t)j0 * 64 + lane];
    u32 u1 = h32[(size_t)j1 * 64 + lane];
    u32 u2 = h32[(size_t)j2 * 64 + lane];
    u32 u3 = h32[(size_t)j3 * 64 + lane];
    ax += w0 * bf2f(u0 & 0xffffu); ay += w0 * bf2f(u0 >> 16);
    ax += w1 * bf2f(u1 & 0xffffu); ay += w1 * bf2f(u1 >> 16);
    ax += w2 * bf2f(u2 & 0xffffu); ay += w2 * bf2f(u2 >> 16);
    ax += w3 * bf2f(u3 & 0xffffu); ay += w3 * bf2f(u3 >> 16);
  }
  for (; p < e; p++) {
    int j = col[p]; float wv = wn[p];
    u32 uu = h32[(size_t)j * 64 + lane];
    ax += wv * bf2f(uu & 0xffffu); ay += wv * bf2f(uu >> 16);
  }
  ax = fmaxf(ax + bias[lane * 2], 0.f);
  ay = fmaxf(ay + bias[lane * 2 + 1], 0.f);
  ((u32*)outf)[(size_t)i * 64 + lane] = packbf2(ax, ay);
}

// ---------------- classifier: logits[N][8] = concat(lm,out)[N][256] @ Wc[256][8] + bc ----------

__global__ __launch_bounds__(256) void classifier_kernel(
    const u16* __restrict__ lm, const u16* __restrict__ feat,
    const float* __restrict__ Wc, const float* __restrict__ bc,
    float* __restrict__ out, int N)
{
  __shared__ float sW[256 * 8];
  __shared__ u16 sF[32 * 264];                 // 32 nodes x 256 feats, +8 pad vs bank conflicts
  int t = threadIdx.x;
#pragma unroll
  for (int r = 0; r < 8; r++) sW[t + r * 256] = Wc[t + r * 256];
  int n0 = blockIdx.x * 32;
  u32* sF32 = (u32*)sF;
#pragma unroll
  for (int r = 0; r < 8; r++) {
    int idx = t + r * 256;                     // 0..2047
    int n = idx >> 6, cpos = idx & 63;         // 64 u32 per half-row
    int gn = n0 + n; if (gn >= N) gn = N - 1;
    sF32[n * 132 + cpos]      = ((const u32*)lm)[(size_t)gn * 64 + cpos];
    sF32[n * 132 + 64 + cpos] = ((const u32*)feat)[(size_t)gn * 64 + cpos];
  }
  __syncthreads();
  int n = t >> 3, c = t & 7;
  int gn = n0 + n;
  float sum = bc[c];
#pragma unroll 16
  for (int k = 0; k < 256; k++)
    sum += bf2f((u32)sF[n * 264 + k]) * sW[k * 8 + c];
  if (gn < N) out[(size_t)gn * 8 + c] = sum;
}

// ---------------- launcher ----------------

static inline char* bump(char*& p, size_t bytes) {
  char* r = p;
  p += (bytes + 255) & ~(size_t)255;
  return r;
}

extern "C" void kernel_launch(void* const* d_in, const int* in_sizes, int n_in,
                              void* d_out, int out_size, void* d_ws, size_t ws_size,
                              hipStream_t stream) {
  const float* X   = (const float*)d_in[0];   // [N][1024]
  const int*   EI  = (const int*)  d_in[1];   // [2][E]
  const float* Wlm = (const float*)d_in[2];   // [1024][128]
  const float* blm = (const float*)d_in[3];   // [128]
  const float* Wg  = (const float*)d_in[4];   // [L][128][128]
  const float* bg  = (const float*)d_in[5];   // [L][128]
  const float* Wc  = (const float*)d_in[6];   // [256][8]
  const float* bc  = (const float*)d_in[7];   // [8]
  float* out = (float*)d_out;

  const int N = in_sizes[0] / 1024;
  const int E = in_sizes[1] / 2;
  const int L = in_sizes[4] / (128 * 128);

  char* wp = (char*)d_ws;
  int*   counts  = (int*)  bump(wp, (size_t)N * 4);
  int*   cursor  = (int*)  bump(wp, (size_t)N * 4);
  int*   offs    = (int*)  bump(wp, (size_t)(N + 1) * 4);
  float* dinv    = (float*)bump(wp, (size_t)N * 4);
  int*   partials= (int*)  bump(wp, 1024 * 4);
  int*   colA    = (int*)  bump(wp, (size_t)E * 4);
  float* wnA     = (float*)bump(wp, (size_t)E * 4);
  u16*   WlmT    = (u16*)  bump(wp, (size_t)1024 * 128 * 2);
  u16*   WgT     = (u16*)  bump(wp, (size_t)L * 128 * 128 * 2);
  u16*   lmB     = (u16*)  bump(wp, (size_t)N * 128 * 2);
  u16*   hB      = (u16*)  bump(wp, (size_t)N * 128 * 2);
  u16*   featB   = (u16*)  bump(wp, (size_t)N * 128 * 2);

  hipMemsetAsync(counts, 0, (size_t)N * 4, stream);
  hipMemsetAsync(cursor, 0, (size_t)N * 4, stream);

  const int* srcp = EI;
  const int* dstp = EI + E;

  count_kernel<<<(E + 255) / 256, 256, 0, stream>>>(dstp, counts, E);
  dinv_kernel<<<(N + 255) / 256, 256, 0, stream>>>(counts, dinv, N);

  int NB = (N + 1023) / 1024;   // 98 for N=100000; single-block scan supports NB<=256
  scan_partial<<<NB, 256, 0, stream>>>(counts, partials, N);
  scan_partials_excl<<<1, 256, 0, stream>>>(partials, NB, offs, N, E);
  scan_final<<<NB, 256, 0, stream>>>(counts, partials, offs, N);
  fill_kernel<<<(E + 255) / 256, 256, 0, stream>>>(srcp, dstp, offs, cursor, dinv, colA, wnA, E);

  prep_wlm<<<(1024 * 128 + 255) / 256, 256, 0, stream>>>(Wlm, WlmT);
  prep_wgcn<<<(L * 128 * 128 + 255) / 256, 256, 0, stream>>>(Wg, WgT, L * 128 * 128);

  int GB = (N + 127) / 128;
  gemm_kernel<1024, true, true><<<GB, 256, 0, stream>>>(X, WlmT, blm, lmB, N);

  const u16* cur = lmB;
  for (int l = 0; l < L; l++) {
    gemm_kernel<128, false, false><<<GB, 256, 0, stream>>>(cur, WgT + (size_t)l * 16384, nullptr, hB, N);
    aggregate_kernel<<<(N + 3) / 4, 256, 0, stream>>>(hB, offs, colA, wnA, dinv, bg + (size_t)l * 128, featB, N);
    cur = featB;
  }

  classifier_kernel<<<(N + 31) / 32, 256, 0, stream>>>(lmB, featB, Wc, bc, out, N);
}